// Round 3
// baseline (592.011 us; speedup 1.0000x reference)
//
#include <hip/hip_runtime.h>

#define NNODES 100000
#define SCAN_ELEMS 1024   // elements per scan block (256 threads x 4)
#define BIN_SHIFT 5       // 32 nodes per bin -> 3125 bins

// ---------------- edge dtype sniffer (int64 vs int32) ----------------
__global__ void detect_kernel(const int* __restrict__ raw, int* __restrict__ flag) {
    __shared__ int cnt;
    if (threadIdx.x == 0) cnt = 0;
    __syncthreads();
    if (threadIdx.x < 100) {
        // if data is int64, odd int32 words are the (zero) high halves
        if (raw[2 * threadIdx.x + 1] == 0) atomicAdd(&cnt, 1);
    }
    __syncthreads();
    if (threadIdx.x == 0) *flag = (cnt > 50) ? 1 : 0;
}

// ---------------- degree (reads raw edges directly) ----------------
__global__ void degree_kernel(const int* __restrict__ raw, int* __restrict__ indeg,
                              int E, const int* __restrict__ flag) {
    int e = blockIdx.x * blockDim.x + threadIdx.x;
    if (e >= E) return;
    int d = (*flag) ? raw[2 * E + 2 * e] : raw[E + e];
    atomicAdd(&indeg[d], 1);
}

__global__ void dinv_kernel(const int* __restrict__ indeg, float* __restrict__ dinv, int n) {
    int i = blockIdx.x * blockDim.x + threadIdx.x;
    if (i >= n) return;
    dinv[i] = rsqrtf((float)(indeg[i] + 1));   // +1 self loop; always > 0
}

// ---------------- device-wide exclusive scan: indeg -> ptr[0..n] ----------------
__global__ __launch_bounds__(256) void scan_partial_kernel(const int* __restrict__ indeg,
                                                           int* __restrict__ bsum, int n) {
    int base = blockIdx.x * SCAN_ELEMS + threadIdx.x * 4;
    int s = 0;
    if (base + 3 < n) {
        int4 v = *reinterpret_cast<const int4*>(&indeg[base]);
        s = v.x + v.y + v.z + v.w;
    } else {
        for (int i = base; i < n && i < base + 4; ++i) s += indeg[i];
    }
#pragma unroll
    for (int d = 32; d; d >>= 1) s += __shfl_down(s, d, 64);
    __shared__ int ws[4];
    int wid = threadIdx.x >> 6;
    if ((threadIdx.x & 63) == 0) ws[wid] = s;
    __syncthreads();
    if (threadIdx.x == 0) bsum[blockIdx.x] = ws[0] + ws[1] + ws[2] + ws[3];
}

// nb <= 128 partials; also writes ptr[n] = total edge count
__global__ void scan_partials_kernel(const int* __restrict__ bsum, int* __restrict__ boff,
                                     int* __restrict__ ptr_n, int nb) {
    __shared__ int s[128];
    int t = threadIdx.x;
    s[t] = (t < nb) ? bsum[t] : 0;
    __syncthreads();
    for (int d = 1; d < 128; d <<= 1) {
        int v = (t >= d) ? s[t - d] : 0;
        __syncthreads();
        s[t] += v;
        __syncthreads();
    }
    if (t < nb) boff[t] = (t == 0) ? 0 : s[t - 1];
    if (t == 127) *ptr_n = s[127];
}

__global__ __launch_bounds__(256) void scan_write_kernel(const int* __restrict__ indeg,
                                                         const int* __restrict__ boff,
                                                         int* __restrict__ ptr, int n) {
    __shared__ int ts[256];
    int base = blockIdx.x * SCAN_ELEMS + threadIdx.x * 4;
    int v0 = 0, v1 = 0, v2 = 0, v3 = 0;
    if (base + 3 < n) {
        int4 v = *reinterpret_cast<const int4*>(&indeg[base]);
        v0 = v.x; v1 = v.y; v2 = v.z; v3 = v.w;
    } else {
        if (base < n)     v0 = indeg[base];
        if (base + 1 < n) v1 = indeg[base + 1];
        if (base + 2 < n) v2 = indeg[base + 2];
    }
    ts[threadIdx.x] = v0 + v1 + v2 + v3;
    __syncthreads();
    for (int d = 1; d < 256; d <<= 1) {
        int t = (threadIdx.x >= d) ? ts[threadIdx.x - d] : 0;
        __syncthreads();
        ts[threadIdx.x] += t;
        __syncthreads();
    }
    int run = boff[blockIdx.x] + ((threadIdx.x == 0) ? 0 : ts[threadIdx.x - 1]);
    if (base < n)     { ptr[base] = run;     run += v0; }
    if (base + 1 < n) { ptr[base + 1] = run; run += v1; }
    if (base + 2 < n) { ptr[base + 2] = run; run += v2; }
    if (base + 3 < n) { ptr[base + 3] = run; }
}

// per-node cursor AND per-bin cursor init (bins aligned to CSR: binoff = ptr[b<<BIN_SHIFT])
__global__ void cursor_kernel(const int* __restrict__ ptr, int* __restrict__ cursor,
                              int* __restrict__ bincur, int n, int nbins) {
    int i = blockIdx.x * blockDim.x + threadIdx.x;
    if (i < n) cursor[i] = ptr[i];
    if (i < nbins) bincur[i] = ptr[i << BIN_SHIFT];
}

// pass 1: scatter packed (src,dst) into bin-sorted order (bins = dst>>BIN_SHIFT)
__global__ void binscatter_kernel(const int* __restrict__ raw, int* __restrict__ bincur,
                                  int2* __restrict__ packed, int E, const int* __restrict__ flag) {
    int e = blockIdx.x * blockDim.x + threadIdx.x;
    if (e >= E) return;
    int s, d;
    if (*flag) {                       // int64 storage, little-endian low words
        s = raw[2 * e];
        d = raw[2 * E + 2 * e];
    } else {                           // int32 storage
        s = raw[e];
        d = raw[E + e];
    }
    int pos = atomicAdd(&bincur[d >> BIN_SHIFT], 1);
    packed[pos] = make_int2(s, d);
}

// pass 2: bin-local CSR fill (reads bin-sorted edges, writes land in ~4KB windows)
__global__ void csrfill_kernel(const int2* __restrict__ packed, const float* __restrict__ dinv,
                               int* __restrict__ cursor, int* __restrict__ col,
                               float* __restrict__ wgt, int E) {
    int e = blockIdx.x * blockDim.x + threadIdx.x;
    if (e >= E) return;
    int2 sd = packed[e];
    int pos = atomicAdd(&cursor[sd.y], 1);
    col[pos] = sd.x;
    wgt[pos] = dinv[sd.x];
}

// ---------------- GEMM1: [M,256] @ [256,64] -> [M,64] ----------------
__global__ __launch_bounds__(256) void gemm1_kernel(const float* __restrict__ x,
                                                    const float* __restrict__ W,
                                                    float* __restrict__ H, int M) {
    __shared__ float xs[64][65];
    __shared__ float ws[64][64];
    int tid = threadIdx.x;
    int bm = blockIdx.x * 64;
    int ty = tid >> 4, tx = tid & 15;
    float acc[4][4] = {};
    for (int kt = 0; kt < 256; kt += 64) {
#pragma unroll
        for (int i = 0; i < 4; ++i) {
            int lin = (tid << 2) + i;          // float4 index 0..1023
            int r = lin >> 4;
            int c = (lin & 15) << 2;
            float4 v = make_float4(0.f, 0.f, 0.f, 0.f);
            int gr = bm + r;
            if (gr < M) v = *reinterpret_cast<const float4*>(&x[(size_t)gr * 256 + kt + c]);
            xs[r][c] = v.x; xs[r][c + 1] = v.y; xs[r][c + 2] = v.z; xs[r][c + 3] = v.w;
        }
#pragma unroll
        for (int i = 0; i < 4; ++i) {
            int lin = (tid << 2) + i;
            int r = lin >> 4;
            int c = (lin & 15) << 2;
            *reinterpret_cast<float4*>(&ws[r][c]) =
                *reinterpret_cast<const float4*>(&W[(size_t)(kt + r) * 64 + c]);
        }
        __syncthreads();
#pragma unroll 8
        for (int kk = 0; kk < 64; ++kk) {
            float a[4], b[4];
#pragma unroll
            for (int i = 0; i < 4; ++i) a[i] = xs[ty * 4 + i][kk];
            float4 bv = *reinterpret_cast<const float4*>(&ws[kk][tx << 2]);
            b[0] = bv.x; b[1] = bv.y; b[2] = bv.z; b[3] = bv.w;
#pragma unroll
            for (int i = 0; i < 4; ++i)
#pragma unroll
                for (int j = 0; j < 4; ++j)
                    acc[i][j] = fmaf(a[i], b[j], acc[i][j]);
        }
        __syncthreads();
    }
#pragma unroll
    for (int i = 0; i < 4; ++i) {
        int gr = bm + ty * 4 + i;
        if (gr < M) {
            float4 o; o.x = acc[i][0]; o.y = acc[i][1]; o.z = acc[i][2]; o.w = acc[i][3];
            *reinterpret_cast<float4*>(&H[(size_t)gr * 64 + (tx << 2)]) = o;
        }
    }
}

// ---------------- aggregation: out[i,:] = dinv[i]*(sum_j w[j]*h[col[j],:] + dinv[i]*h[i,:]) ----------------
__global__ __launch_bounds__(256) void aggregate_kernel(const float* __restrict__ h,
                                                        const int* __restrict__ ptr,
                                                        const int* __restrict__ col,
                                                        const float* __restrict__ wgt,
                                                        const float* __restrict__ dinv,
                                                        const float* __restrict__ bias,
                                                        float* __restrict__ out, int n, int relu) {
    int node = (blockIdx.x << 2) + (threadIdx.x >> 6);
    if (node >= n) return;
    int lane = threadIdx.x & 63;
    float di = dinv[node];
    float acc = di * h[(size_t)node * 64 + lane];   // self-loop (di factored out)
    int p = ptr[node];
    int e = ptr[node + 1];
    for (; p + 1 < e; p += 2) {
        int   j0 = col[p],  j1 = col[p + 1];
        float w0 = wgt[p],  w1 = wgt[p + 1];
        float h0 = h[(size_t)j0 * 64 + lane];
        float h1v = h[(size_t)j1 * 64 + lane];
        acc = fmaf(w0, h0, acc);
        acc = fmaf(w1, h1v, acc);
    }
    if (p < e) acc = fmaf(wgt[p], h[(size_t)col[p] * 64 + lane], acc);
    float v = acc * di;
    if (bias) v += bias[lane];
    if (relu) v = fmaxf(v, 0.f);
    out[(size_t)node * 64 + lane] = v;
}

// ---------------- GEMM2: [M,64] @ [64,128] + b -> [M,128] ----------------
__global__ __launch_bounds__(256) void gemm2_kernel(const float* __restrict__ A,
                                                    const float* __restrict__ W,
                                                    const float* __restrict__ bias,
                                                    float* __restrict__ out, int M) {
    __shared__ float as[64][65];
    __shared__ float ws[64][128];
    int tid = threadIdx.x;
    int bm = blockIdx.x * 64;
    int ty = tid >> 4, tx = tid & 15;
#pragma unroll
    for (int i = 0; i < 4; ++i) {
        int lin = (tid << 2) + i;
        int r = lin >> 4;
        int c = (lin & 15) << 2;
        float4 v = make_float4(0.f, 0.f, 0.f, 0.f);
        int gr = bm + r;
        if (gr < M) v = *reinterpret_cast<const float4*>(&A[(size_t)gr * 64 + c]);
        as[r][c] = v.x; as[r][c + 1] = v.y; as[r][c + 2] = v.z; as[r][c + 3] = v.w;
    }
#pragma unroll
    for (int i = 0; i < 8; ++i) {
        int lin = tid + (i << 8);              // 0..2047 float4s
        int r = lin >> 5;
        int c = (lin & 31) << 2;
        *reinterpret_cast<float4*>(&ws[r][c]) =
            *reinterpret_cast<const float4*>(&W[(size_t)r * 128 + c]);
    }
    __syncthreads();
    float acc[4][8] = {};
#pragma unroll 8
    for (int kk = 0; kk < 64; ++kk) {
        float a[4];
#pragma unroll
        for (int i = 0; i < 4; ++i) a[i] = as[ty * 4 + i][kk];
        float b[8];
        float4 b0 = *reinterpret_cast<const float4*>(&ws[kk][tx * 8]);
        float4 b1 = *reinterpret_cast<const float4*>(&ws[kk][tx * 8 + 4]);
        b[0] = b0.x; b[1] = b0.y; b[2] = b0.z; b[3] = b0.w;
        b[4] = b1.x; b[5] = b1.y; b[6] = b1.z; b[7] = b1.w;
#pragma unroll
        for (int i = 0; i < 4; ++i)
#pragma unroll
            for (int j = 0; j < 8; ++j)
                acc[i][j] = fmaf(a[i], b[j], acc[i][j]);
    }
#pragma unroll
    for (int i = 0; i < 4; ++i) {
        int gr = bm + ty * 4 + i;
        if (gr >= M) continue;
#pragma unroll
        for (int jv = 0; jv < 2; ++jv) {
            int cbase = tx * 8 + jv * 4;
            float4 o;
            o.x = acc[i][jv * 4 + 0] + bias[cbase + 0];
            o.y = acc[i][jv * 4 + 1] + bias[cbase + 1];
            o.z = acc[i][jv * 4 + 2] + bias[cbase + 2];
            o.w = acc[i][jv * 4 + 3] + bias[cbase + 3];
            *reinterpret_cast<float4*>(&out[(size_t)gr * 128 + cbase]) = o;
        }
    }
}

extern "C" void kernel_launch(void* const* d_in, const int* in_sizes, int n_in,
                              void* d_out, int out_size, void* d_ws, size_t ws_size,
                              hipStream_t stream) {
    const float* x  = (const float*)d_in[0];
    const int*   ei = (const int*)d_in[1];
    const float* W1 = (const float*)d_in[2];
    const float* b1 = (const float*)d_in[3];
    const float* W2 = (const float*)d_in[4];
    const float* b2 = (const float*)d_in[5];
    float* out = (float*)d_out;
    const int n = NNODES;
    const int E = in_sizes[1] / 2;
    const int nbins = (n + (1 << BIN_SHIFT) - 1) >> BIN_SHIFT;

    char* w = (char*)d_ws;
    auto alloc = [&](size_t bytes) {
        char* p = w;
        w += (bytes + 255) & ~(size_t)255;
        return p;
    };
    int*   flag   = (int*)  alloc(4);
    int*   indeg  = (int*)  alloc((size_t)n * 4);
    float* dinv   = (float*)alloc((size_t)n * 4);
    int*   ptr    = (int*)  alloc((size_t)(n + 1) * 4);
    int*   cursor = (int*)  alloc((size_t)n * 4);
    int*   bincur = (int*)  alloc((size_t)nbins * 4);
    int*   bsum   = (int*)  alloc(128 * 4);
    int*   boff   = (int*)  alloc(128 * 4);
    int2*  packed = (int2*) alloc((size_t)E * 8);
    int*   col    = (int*)  alloc((size_t)E * 4);
    float* wgt    = (float*)alloc((size_t)E * 4);
    float* H1     = (float*)alloc((size_t)n * 64 * 4);
    float* h1     = (float*)alloc((size_t)n * 64 * 4);
    float* A2     = H1;   // H1 dead after first aggregation

    hipMemsetAsync(indeg, 0, (size_t)n * 4, stream);

    int eb = (E + 255) / 256;
    int nb = (n + 255) / 256;
    int sb = (n + SCAN_ELEMS - 1) / SCAN_ELEMS;   // 98 scan blocks
    detect_kernel<<<1, 128, 0, stream>>>(ei, flag);
    degree_kernel<<<eb, 256, 0, stream>>>(ei, indeg, E, flag);
    dinv_kernel<<<nb, 256, 0, stream>>>(indeg, dinv, n);
    scan_partial_kernel<<<sb, 256, 0, stream>>>(indeg, bsum, n);
    scan_partials_kernel<<<1, 128, 0, stream>>>(bsum, boff, &ptr[n], sb);
    scan_write_kernel<<<sb, 256, 0, stream>>>(indeg, boff, ptr, n);
    cursor_kernel<<<nb, 256, 0, stream>>>(ptr, cursor, bincur, n, nbins);
    binscatter_kernel<<<eb, 256, 0, stream>>>(ei, bincur, packed, E, flag);
    csrfill_kernel<<<eb, 256, 0, stream>>>(packed, dinv, cursor, col, wgt, E);

    gemm1_kernel<<<(n + 63) / 64, 256, 0, stream>>>(x, W1, H1, n);
    aggregate_kernel<<<(n + 3) / 4, 256, 0, stream>>>(H1, ptr, col, wgt, dinv, b1, h1, n, 1);
    aggregate_kernel<<<(n + 3) / 4, 256, 0, stream>>>(h1, ptr, col, wgt, dinv, nullptr, A2, n, 0);
    gemm2_kernel<<<(n + 63) / 64, 256, 0, stream>>>(A2, W2, b2, out, n);
}

// Round 4
// 447.625 us; speedup vs baseline: 1.3226x; 1.3226x over previous
//
#include <hip/hip_runtime.h>

#define NNODES 100000
#define NPART 8
#define PART (NNODES / NPART)     // 12500 nodes per partition
#define NCHUNK 256                // edge chunks; grid = 8*NCHUNK blocks
#define SCAN_ELEMS 1024           // elements per scan block (256 threads x 4)

// ---------------- edge dtype sniffer (int64 vs int32) ----------------
__global__ void detect_kernel(const int* __restrict__ raw, int* __restrict__ flag) {
    __shared__ int cnt;
    if (threadIdx.x == 0) cnt = 0;
    __syncthreads();
    if (threadIdx.x < 100) {
        // if data is int64, odd int32 words are the (zero) high halves
        if (raw[2 * threadIdx.x + 1] == 0) atomicAdd(&cnt, 1);
    }
    __syncthreads();
    if (threadIdx.x == 0) *flag = (cnt > 50) ? 1 : 0;
}

// ---------------- degree, XCD-partitioned (atomics stay L2-local) ----------------
__global__ __launch_bounds__(256) void degree8_kernel(const int* __restrict__ raw,
                                                      int* __restrict__ indeg,
                                                      int E, int CE, const int* __restrict__ flag) {
    int pid   = blockIdx.x & (NPART - 1);   // ~= this block's XCD (round-robin dispatch)
    int chunk = blockIdx.x >> 3;
    int lo = pid * PART;
    int isI64 = *flag;
    int beg = chunk * CE;
    int end = beg + CE; if (end > E) end = E;
    for (int e = beg + (int)threadIdx.x; e < end; e += 256) {
        int d = isI64 ? raw[2 * E + 2 * e] : raw[E + e];
        if ((unsigned)(d - lo) < (unsigned)PART)
            atomicAdd(&indeg[d], 1);
    }
}

__global__ void dinv_kernel(const int* __restrict__ indeg, float* __restrict__ dinv, int n) {
    int i = blockIdx.x * blockDim.x + threadIdx.x;
    if (i >= n) return;
    dinv[i] = rsqrtf((float)(indeg[i] + 1));   // +1 self loop; always > 0
}

// ---------------- device-wide exclusive scan: indeg -> ptr[0..n] ----------------
__global__ __launch_bounds__(256) void scan_partial_kernel(const int* __restrict__ indeg,
                                                           int* __restrict__ bsum, int n) {
    int base = blockIdx.x * SCAN_ELEMS + threadIdx.x * 4;
    int s = 0;
    if (base + 3 < n) {
        int4 v = *reinterpret_cast<const int4*>(&indeg[base]);
        s = v.x + v.y + v.z + v.w;
    } else {
        for (int i = base; i < n && i < base + 4; ++i) s += indeg[i];
    }
#pragma unroll
    for (int d = 32; d; d >>= 1) s += __shfl_down(s, d, 64);
    __shared__ int ws[4];
    int wid = threadIdx.x >> 6;
    if ((threadIdx.x & 63) == 0) ws[wid] = s;
    __syncthreads();
    if (threadIdx.x == 0) bsum[blockIdx.x] = ws[0] + ws[1] + ws[2] + ws[3];
}

// nb <= 128 partials; also writes ptr[n] = total edge count
__global__ void scan_partials_kernel(const int* __restrict__ bsum, int* __restrict__ boff,
                                     int* __restrict__ ptr_n, int nb) {
    __shared__ int s[128];
    int t = threadIdx.x;
    s[t] = (t < nb) ? bsum[t] : 0;
    __syncthreads();
    for (int d = 1; d < 128; d <<= 1) {
        int v = (t >= d) ? s[t - d] : 0;
        __syncthreads();
        s[t] += v;
        __syncthreads();
    }
    if (t < nb) boff[t] = (t == 0) ? 0 : s[t - 1];
    if (t == 127) *ptr_n = s[127];
}

__global__ __launch_bounds__(256) void scan_write_kernel(const int* __restrict__ indeg,
                                                         const int* __restrict__ boff,
                                                         int* __restrict__ ptr, int n) {
    __shared__ int ts[256];
    int base = blockIdx.x * SCAN_ELEMS + threadIdx.x * 4;
    int v0 = 0, v1 = 0, v2 = 0, v3 = 0;
    if (base + 3 < n) {
        int4 v = *reinterpret_cast<const int4*>(&indeg[base]);
        v0 = v.x; v1 = v.y; v2 = v.z; v3 = v.w;
    } else {
        if (base < n)     v0 = indeg[base];
        if (base + 1 < n) v1 = indeg[base + 1];
        if (base + 2 < n) v2 = indeg[base + 2];
    }
    ts[threadIdx.x] = v0 + v1 + v2 + v3;
    __syncthreads();
    for (int d = 1; d < 256; d <<= 1) {
        int t = (threadIdx.x >= d) ? ts[threadIdx.x - d] : 0;
        __syncthreads();
        ts[threadIdx.x] += t;
        __syncthreads();
    }
    int run = boff[blockIdx.x] + ((threadIdx.x == 0) ? 0 : ts[threadIdx.x - 1]);
    if (base < n)     { ptr[base] = run;     run += v0; }
    if (base + 1 < n) { ptr[base + 1] = run; run += v1; }
    if (base + 2 < n) { ptr[base + 2] = run; run += v2; }
    if (base + 3 < n) { ptr[base + 3] = run; }
}

__global__ void cursor_kernel(const int* __restrict__ ptr, int* __restrict__ cursor, int n) {
    int i = blockIdx.x * blockDim.x + threadIdx.x;
    if (i < n) cursor[i] = ptr[i];
}

// ---------------- CSR fill, XCD-partitioned: packed (col, wgt) int2 ----------------
__global__ __launch_bounds__(256) void fill8_kernel(const int* __restrict__ raw,
                                                    const float* __restrict__ dinv,
                                                    int* __restrict__ cursor,
                                                    int2* __restrict__ cw,
                                                    int E, int CE, const int* __restrict__ flag) {
    int pid   = blockIdx.x & (NPART - 1);
    int chunk = blockIdx.x >> 3;
    int lo = pid * PART;
    int isI64 = *flag;
    int beg = chunk * CE;
    int end = beg + CE; if (end > E) end = E;
    for (int e = beg + (int)threadIdx.x; e < end; e += 256) {
        int d = isI64 ? raw[2 * E + 2 * e] : raw[E + e];
        if ((unsigned)(d - lo) < (unsigned)PART) {
            int s = isI64 ? raw[2 * e] : raw[e];
            int pos = atomicAdd(&cursor[d], 1);
            cw[pos] = make_int2(s, __float_as_int(dinv[s]));
        }
    }
}

// ---------------- GEMM1: [M,256] @ [256,64] -> [M,64] ----------------
__global__ __launch_bounds__(256) void gemm1_kernel(const float* __restrict__ x,
                                                    const float* __restrict__ W,
                                                    float* __restrict__ H, int M) {
    __shared__ float xs[64][65];
    __shared__ float ws[64][64];
    int tid = threadIdx.x;
    int bm = blockIdx.x * 64;
    int ty = tid >> 4, tx = tid & 15;
    float acc[4][4] = {};
    for (int kt = 0; kt < 256; kt += 64) {
#pragma unroll
        for (int i = 0; i < 4; ++i) {
            int lin = (tid << 2) + i;          // float4 index 0..1023
            int r = lin >> 4;
            int c = (lin & 15) << 2;
            float4 v = make_float4(0.f, 0.f, 0.f, 0.f);
            int gr = bm + r;
            if (gr < M) v = *reinterpret_cast<const float4*>(&x[(size_t)gr * 256 + kt + c]);
            xs[r][c] = v.x; xs[r][c + 1] = v.y; xs[r][c + 2] = v.z; xs[r][c + 3] = v.w;
        }
#pragma unroll
        for (int i = 0; i < 4; ++i) {
            int lin = (tid << 2) + i;
            int r = lin >> 4;
            int c = (lin & 15) << 2;
            *reinterpret_cast<float4*>(&ws[r][c]) =
                *reinterpret_cast<const float4*>(&W[(size_t)(kt + r) * 64 + c]);
        }
        __syncthreads();
#pragma unroll 8
        for (int kk = 0; kk < 64; ++kk) {
            float a[4], b[4];
#pragma unroll
            for (int i = 0; i < 4; ++i) a[i] = xs[ty * 4 + i][kk];
            float4 bv = *reinterpret_cast<const float4*>(&ws[kk][tx << 2]);
            b[0] = bv.x; b[1] = bv.y; b[2] = bv.z; b[3] = bv.w;
#pragma unroll
            for (int i = 0; i < 4; ++i)
#pragma unroll
                for (int j = 0; j < 4; ++j)
                    acc[i][j] = fmaf(a[i], b[j], acc[i][j]);
        }
        __syncthreads();
    }
#pragma unroll
    for (int i = 0; i < 4; ++i) {
        int gr = bm + ty * 4 + i;
        if (gr < M) {
            float4 o; o.x = acc[i][0]; o.y = acc[i][1]; o.z = acc[i][2]; o.w = acc[i][3];
            *reinterpret_cast<float4*>(&H[(size_t)gr * 64 + (tx << 2)]) = o;
        }
    }
}

// ---------------- aggregation: out[i,:] = dinv[i]*(sum_j w[j]*h[col[j],:] + dinv[i]*h[i,:]) ----------------
__global__ __launch_bounds__(256) void aggregate_kernel(const float* __restrict__ h,
                                                        const int* __restrict__ ptr,
                                                        const int2* __restrict__ cw,
                                                        const float* __restrict__ dinv,
                                                        const float* __restrict__ bias,
                                                        float* __restrict__ out, int n, int relu) {
    int node = (blockIdx.x << 2) + (threadIdx.x >> 6);
    if (node >= n) return;
    int lane = threadIdx.x & 63;
    float di = dinv[node];
    float acc = di * h[(size_t)node * 64 + lane];   // self-loop (di factored out)
    int p = ptr[node];
    int e = ptr[node + 1];
    for (; p + 1 < e; p += 2) {
        int2 c0 = cw[p], c1 = cw[p + 1];
        float h0 = h[(size_t)c0.x * 64 + lane];
        float h1v = h[(size_t)c1.x * 64 + lane];
        acc = fmaf(__int_as_float(c0.y), h0, acc);
        acc = fmaf(__int_as_float(c1.y), h1v, acc);
    }
    if (p < e) {
        int2 c0 = cw[p];
        acc = fmaf(__int_as_float(c0.y), h[(size_t)c0.x * 64 + lane], acc);
    }
    float v = acc * di;
    if (bias) v += bias[lane];
    if (relu) v = fmaxf(v, 0.f);
    out[(size_t)node * 64 + lane] = v;
}

// ---------------- GEMM2: [M,64] @ [64,128] + b -> [M,128] ----------------
__global__ __launch_bounds__(256) void gemm2_kernel(const float* __restrict__ A,
                                                    const float* __restrict__ W,
                                                    const float* __restrict__ bias,
                                                    float* __restrict__ out, int M) {
    __shared__ float as[64][65];
    __shared__ float ws[64][128];
    int tid = threadIdx.x;
    int bm = blockIdx.x * 64;
    int ty = tid >> 4, tx = tid & 15;
#pragma unroll
    for (int i = 0; i < 4; ++i) {
        int lin = (tid << 2) + i;
        int r = lin >> 4;
        int c = (lin & 15) << 2;
        float4 v = make_float4(0.f, 0.f, 0.f, 0.f);
        int gr = bm + r;
        if (gr < M) v = *reinterpret_cast<const float4*>(&A[(size_t)gr * 64 + c]);
        as[r][c] = v.x; as[r][c + 1] = v.y; as[r][c + 2] = v.z; as[r][c + 3] = v.w;
    }
#pragma unroll
    for (int i = 0; i < 8; ++i) {
        int lin = tid + (i << 8);              // 0..2047 float4s
        int r = lin >> 5;
        int c = (lin & 31) << 2;
        *reinterpret_cast<float4*>(&ws[r][c]) =
            *reinterpret_cast<const float4*>(&W[(size_t)r * 128 + c]);
    }
    __syncthreads();
    float acc[4][8] = {};
#pragma unroll 8
    for (int kk = 0; kk < 64; ++kk) {
        float a[4];
#pragma unroll
        for (int i = 0; i < 4; ++i) a[i] = as[ty * 4 + i][kk];
        float b[8];
        float4 b0 = *reinterpret_cast<const float4*>(&ws[kk][tx * 8]);
        float4 b1 = *reinterpret_cast<const float4*>(&ws[kk][tx * 8 + 4]);
        b[0] = b0.x; b[1] = b0.y; b[2] = b0.z; b[3] = b0.w;
        b[4] = b1.x; b[5] = b1.y; b[6] = b1.z; b[7] = b1.w;
#pragma unroll
        for (int i = 0; i < 4; ++i)
#pragma unroll
            for (int j = 0; j < 8; ++j)
                acc[i][j] = fmaf(a[i], b[j], acc[i][j]);
    }
#pragma unroll
    for (int i = 0; i < 4; ++i) {
        int gr = bm + ty * 4 + i;
        if (gr >= M) continue;
#pragma unroll
        for (int jv = 0; jv < 2; ++jv) {
            int cbase = tx * 8 + jv * 4;
            float4 o;
            o.x = acc[i][jv * 4 + 0] + bias[cbase + 0];
            o.y = acc[i][jv * 4 + 1] + bias[cbase + 1];
            o.z = acc[i][jv * 4 + 2] + bias[cbase + 2];
            o.w = acc[i][jv * 4 + 3] + bias[cbase + 3];
            *reinterpret_cast<float4*>(&out[(size_t)gr * 128 + cbase]) = o;
        }
    }
}

extern "C" void kernel_launch(void* const* d_in, const int* in_sizes, int n_in,
                              void* d_out, int out_size, void* d_ws, size_t ws_size,
                              hipStream_t stream) {
    const float* x  = (const float*)d_in[0];
    const int*   ei = (const int*)d_in[1];
    const float* W1 = (const float*)d_in[2];
    const float* b1 = (const float*)d_in[3];
    const float* W2 = (const float*)d_in[4];
    const float* b2 = (const float*)d_in[5];
    float* out = (float*)d_out;
    const int n = NNODES;
    const int E = in_sizes[1] / 2;
    const int CE = (E + NCHUNK - 1) / NCHUNK;

    char* w = (char*)d_ws;
    auto alloc = [&](size_t bytes) {
        char* p = w;
        w += (bytes + 255) & ~(size_t)255;
        return p;
    };
    int*   flag   = (int*)  alloc(4);
    int*   indeg  = (int*)  alloc((size_t)n * 4);
    float* dinv   = (float*)alloc((size_t)n * 4);
    int*   ptr    = (int*)  alloc((size_t)(n + 1) * 4);
    int*   cursor = (int*)  alloc((size_t)n * 4);
    int*   bsum   = (int*)  alloc(128 * 4);
    int*   boff   = (int*)  alloc(128 * 4);
    int2*  cw     = (int2*) alloc((size_t)E * 8);
    float* H1     = (float*)alloc((size_t)n * 64 * 4);
    float* h1     = (float*)alloc((size_t)n * 64 * 4);
    float* A2     = H1;   // H1 dead after first aggregation

    hipMemsetAsync(indeg, 0, (size_t)n * 4, stream);

    int nb = (n + 255) / 256;
    int sb = (n + SCAN_ELEMS - 1) / SCAN_ELEMS;   // 98 scan blocks
    detect_kernel<<<1, 128, 0, stream>>>(ei, flag);
    degree8_kernel<<<NPART * NCHUNK, 256, 0, stream>>>(ei, indeg, E, CE, flag);
    dinv_kernel<<<nb, 256, 0, stream>>>(indeg, dinv, n);
    scan_partial_kernel<<<sb, 256, 0, stream>>>(indeg, bsum, n);
    scan_partials_kernel<<<1, 128, 0, stream>>>(bsum, boff, &ptr[n], sb);
    scan_write_kernel<<<sb, 256, 0, stream>>>(indeg, boff, ptr, n);
    cursor_kernel<<<nb, 256, 0, stream>>>(ptr, cursor, n);
    fill8_kernel<<<NPART * NCHUNK, 256, 0, stream>>>(ei, dinv, cursor, cw, E, CE, flag);

    gemm1_kernel<<<(n + 63) / 64, 256, 0, stream>>>(x, W1, H1, n);
    aggregate_kernel<<<(n + 3) / 4, 256, 0, stream>>>(H1, ptr, cw, dinv, b1, h1, n, 1);
    aggregate_kernel<<<(n + 3) / 4, 256, 0, stream>>>(h1, ptr, cw, dinv, nullptr, A2, n, 0);
    gemm2_kernel<<<(n + 63) / 64, 256, 0, stream>>>(A2, W2, b2, out, n);
}

// Round 5
// 376.036 us; speedup vs baseline: 1.5743x; 1.1904x over previous
//
#include <hip/hip_runtime.h>

#define NNODES 100000
#define NPART 8
#define PART (NNODES / NPART)     // 12500 nodes per partition
#define NCHUNK 256                // edge chunks; grid = 8*NCHUNK blocks
#define SCAN_ELEMS 1024           // elements per scan block (256 threads x 4)

// ---------------- edge dtype sniffer (int64 vs int32) ----------------
__global__ void detect_kernel(const int* __restrict__ raw, int* __restrict__ flag) {
    __shared__ int cnt;
    if (threadIdx.x == 0) cnt = 0;
    __syncthreads();
    if (threadIdx.x < 100) {
        // if data is int64, odd int32 words are the (zero) high halves
        if (raw[2 * threadIdx.x + 1] == 0) atomicAdd(&cnt, 1);
    }
    __syncthreads();
    if (threadIdx.x == 0) *flag = (cnt > 50) ? 1 : 0;
}

// ---------------- degree, XCD-partitioned (atomics stay L2-local) ----------------
__global__ __launch_bounds__(256) void degree8_kernel(const int* __restrict__ raw,
                                                      int* __restrict__ indeg,
                                                      int E, int CE, const int* __restrict__ flag) {
    int pid   = blockIdx.x & (NPART - 1);   // ~= this block's XCD (round-robin dispatch)
    int chunk = blockIdx.x >> 3;
    int lo = pid * PART;
    int isI64 = *flag;
    int beg = chunk * CE;
    int end = beg + CE; if (end > E) end = E;
    for (int e = beg + (int)threadIdx.x; e < end; e += 256) {
        int d = isI64 ? raw[2 * E + 2 * e] : raw[E + e];
        if ((unsigned)(d - lo) < (unsigned)PART)
            atomicAdd(&indeg[d], 1);
    }
}

__global__ void dinv_kernel(const int* __restrict__ indeg, float* __restrict__ dinv, int n) {
    int i = blockIdx.x * blockDim.x + threadIdx.x;
    if (i >= n) return;
    dinv[i] = rsqrtf((float)(indeg[i] + 1));   // +1 self loop; always > 0
}

// ---------------- device-wide exclusive scan: indeg -> ptr[0..n] ----------------
__global__ __launch_bounds__(256) void scan_partial_kernel(const int* __restrict__ indeg,
                                                           int* __restrict__ bsum, int n) {
    int base = blockIdx.x * SCAN_ELEMS + threadIdx.x * 4;
    int s = 0;
    if (base + 3 < n) {
        int4 v = *reinterpret_cast<const int4*>(&indeg[base]);
        s = v.x + v.y + v.z + v.w;
    } else {
        for (int i = base; i < n && i < base + 4; ++i) s += indeg[i];
    }
#pragma unroll
    for (int d = 32; d; d >>= 1) s += __shfl_down(s, d, 64);
    __shared__ int ws[4];
    int wid = threadIdx.x >> 6;
    if ((threadIdx.x & 63) == 0) ws[wid] = s;
    __syncthreads();
    if (threadIdx.x == 0) bsum[blockIdx.x] = ws[0] + ws[1] + ws[2] + ws[3];
}

// nb <= 128 partials; also writes ptr[n] = total edge count
__global__ void scan_partials_kernel(const int* __restrict__ bsum, int* __restrict__ boff,
                                     int* __restrict__ ptr_n, int nb) {
    __shared__ int s[128];
    int t = threadIdx.x;
    s[t] = (t < nb) ? bsum[t] : 0;
    __syncthreads();
    for (int d = 1; d < 128; d <<= 1) {
        int v = (t >= d) ? s[t - d] : 0;
        __syncthreads();
        s[t] += v;
        __syncthreads();
    }
    if (t < nb) boff[t] = (t == 0) ? 0 : s[t - 1];
    if (t == 127) *ptr_n = s[127];
}

__global__ __launch_bounds__(256) void scan_write_kernel(const int* __restrict__ indeg,
                                                         const int* __restrict__ boff,
                                                         int* __restrict__ ptr, int n) {
    __shared__ int ts[256];
    int base = blockIdx.x * SCAN_ELEMS + threadIdx.x * 4;
    int v0 = 0, v1 = 0, v2 = 0, v3 = 0;
    if (base + 3 < n) {
        int4 v = *reinterpret_cast<const int4*>(&indeg[base]);
        v0 = v.x; v1 = v.y; v2 = v.z; v3 = v.w;
    } else {
        if (base < n)     v0 = indeg[base];
        if (base + 1 < n) v1 = indeg[base + 1];
        if (base + 2 < n) v2 = indeg[base + 2];
    }
    ts[threadIdx.x] = v0 + v1 + v2 + v3;
    __syncthreads();
    for (int d = 1; d < 256; d <<= 1) {
        int t = (threadIdx.x >= d) ? ts[threadIdx.x - d] : 0;
        __syncthreads();
        ts[threadIdx.x] += t;
        __syncthreads();
    }
    int run = boff[blockIdx.x] + ((threadIdx.x == 0) ? 0 : ts[threadIdx.x - 1]);
    if (base < n)     { ptr[base] = run;     run += v0; }
    if (base + 1 < n) { ptr[base + 1] = run; run += v1; }
    if (base + 2 < n) { ptr[base + 2] = run; run += v2; }
    if (base + 3 < n) { ptr[base + 3] = run; }
}

__global__ void cursor_kernel(const int* __restrict__ ptr, int* __restrict__ cursor, int n) {
    int i = blockIdx.x * blockDim.x + threadIdx.x;
    if (i < n) cursor[i] = ptr[i];
}

// ---------------- CSR fill, XCD-partitioned: packed (col, wgt) int2 ----------------
__global__ __launch_bounds__(256) void fill8_kernel(const int* __restrict__ raw,
                                                    const float* __restrict__ dinv,
                                                    int* __restrict__ cursor,
                                                    int2* __restrict__ cw,
                                                    int E, int CE, const int* __restrict__ flag) {
    int pid   = blockIdx.x & (NPART - 1);
    int chunk = blockIdx.x >> 3;
    int lo = pid * PART;
    int isI64 = *flag;
    int beg = chunk * CE;
    int end = beg + CE; if (end > E) end = E;
    for (int e = beg + (int)threadIdx.x; e < end; e += 256) {
        int d = isI64 ? raw[2 * E + 2 * e] : raw[E + e];
        if ((unsigned)(d - lo) < (unsigned)PART) {
            int s = isI64 ? raw[2 * e] : raw[e];
            int pos = atomicAdd(&cursor[d], 1);
            cw[pos] = make_int2(s, __float_as_int(dinv[s]));
        }
    }
}

// ---------------- GEMM1: [M,256] @ [256,64] -> [M,64] ----------------
__global__ __launch_bounds__(256) void gemm1_kernel(const float* __restrict__ x,
                                                    const float* __restrict__ W,
                                                    float* __restrict__ H, int M) {
    __shared__ float xs[64][65];
    __shared__ float ws[64][64];
    int tid = threadIdx.x;
    int bm = blockIdx.x * 64;
    int ty = tid >> 4, tx = tid & 15;
    float acc[4][4] = {};
    for (int kt = 0; kt < 256; kt += 64) {
#pragma unroll
        for (int i = 0; i < 4; ++i) {
            int lin = (tid << 2) + i;          // float4 index 0..1023
            int r = lin >> 4;
            int c = (lin & 15) << 2;
            float4 v = make_float4(0.f, 0.f, 0.f, 0.f);
            int gr = bm + r;
            if (gr < M) v = *reinterpret_cast<const float4*>(&x[(size_t)gr * 256 + kt + c]);
            xs[r][c] = v.x; xs[r][c + 1] = v.y; xs[r][c + 2] = v.z; xs[r][c + 3] = v.w;
        }
#pragma unroll
        for (int i = 0; i < 4; ++i) {
            int lin = (tid << 2) + i;
            int r = lin >> 4;
            int c = (lin & 15) << 2;
            *reinterpret_cast<float4*>(&ws[r][c]) =
                *reinterpret_cast<const float4*>(&W[(size_t)(kt + r) * 64 + c]);
        }
        __syncthreads();
#pragma unroll 8
        for (int kk = 0; kk < 64; ++kk) {
            float a[4], b[4];
#pragma unroll
            for (int i = 0; i < 4; ++i) a[i] = xs[ty * 4 + i][kk];
            float4 bv = *reinterpret_cast<const float4*>(&ws[kk][tx << 2]);
            b[0] = bv.x; b[1] = bv.y; b[2] = bv.z; b[3] = bv.w;
#pragma unroll
            for (int i = 0; i < 4; ++i)
#pragma unroll
                for (int j = 0; j < 4; ++j)
                    acc[i][j] = fmaf(a[i], b[j], acc[i][j]);
        }
        __syncthreads();
    }
#pragma unroll
    for (int i = 0; i < 4; ++i) {
        int gr = bm + ty * 4 + i;
        if (gr < M) {
            float4 o; o.x = acc[i][0]; o.y = acc[i][1]; o.z = acc[i][2]; o.w = acc[i][3];
            *reinterpret_cast<float4*>(&H[(size_t)gr * 64 + (tx << 2)]) = o;
        }
    }
}

// ---------------- aggregation, quarter-wave version ----------------
// wave = 1 node; 4 quarter-waves of 16 lanes each gather a DIFFERENT edge's
// 256B row as float4 (4 edges per load instruction, 8 in flight with unroll 2).
// out[i,:] = dinv[i]*(sum_j w[j]*h[col[j],:] + dinv[i]*h[i,:]) (+bias, relu)
__global__ __launch_bounds__(256) void aggregate_kernel(const float* __restrict__ h,
                                                        const int* __restrict__ ptr,
                                                        const int2* __restrict__ cw,
                                                        const float* __restrict__ dinv,
                                                        const float* __restrict__ bias,
                                                        float* __restrict__ out, int n, int relu) {
    int node = (blockIdx.x << 2) + (threadIdx.x >> 6);
    if (node >= n) return;
    int lane = threadIdx.x & 63;
    int q    = lane >> 4;              // quarter-wave id 0..3
    int fl   = (lane & 15) << 2;       // feature base 0,4,...,60
    float4 acc = make_float4(0.f, 0.f, 0.f, 0.f);
    int pend = ptr[node + 1];
    int p = ptr[node] + q;             // quarter q takes edges q, q+4, q+8, ...
    for (; p + 4 < pend; p += 8) {     // unroll 2: p and p+4 both valid
        int2 c0 = cw[p];
        int2 c1 = cw[p + 4];
        float4 h0 = *reinterpret_cast<const float4*>(&h[(size_t)c0.x * 64 + fl]);
        float4 h1 = *reinterpret_cast<const float4*>(&h[(size_t)c1.x * 64 + fl]);
        float w0 = __int_as_float(c0.y), w1 = __int_as_float(c1.y);
        acc.x = fmaf(w0, h0.x, acc.x); acc.y = fmaf(w0, h0.y, acc.y);
        acc.z = fmaf(w0, h0.z, acc.z); acc.w = fmaf(w0, h0.w, acc.w);
        acc.x = fmaf(w1, h1.x, acc.x); acc.y = fmaf(w1, h1.y, acc.y);
        acc.z = fmaf(w1, h1.z, acc.z); acc.w = fmaf(w1, h1.w, acc.w);
    }
    if (p < pend) {
        int2 c0 = cw[p];
        float4 h0 = *reinterpret_cast<const float4*>(&h[(size_t)c0.x * 64 + fl]);
        float w0 = __int_as_float(c0.y);
        acc.x = fmaf(w0, h0.x, acc.x); acc.y = fmaf(w0, h0.y, acc.y);
        acc.z = fmaf(w0, h0.z, acc.z); acc.w = fmaf(w0, h0.w, acc.w);
    }
    // combine the 4 quarter-wave partial sums (butterfly over lane bits 4,5)
    acc.x += __shfl_xor(acc.x, 16, 64); acc.y += __shfl_xor(acc.y, 16, 64);
    acc.z += __shfl_xor(acc.z, 16, 64); acc.w += __shfl_xor(acc.w, 16, 64);
    acc.x += __shfl_xor(acc.x, 32, 64); acc.y += __shfl_xor(acc.y, 32, 64);
    acc.z += __shfl_xor(acc.z, 32, 64); acc.w += __shfl_xor(acc.w, 32, 64);
    if (q == 0) {
        float di = dinv[node];
        float4 sv = *reinterpret_cast<const float4*>(&h[(size_t)node * 64 + fl]);
        acc.x = fmaf(di, sv.x, acc.x); acc.y = fmaf(di, sv.y, acc.y);
        acc.z = fmaf(di, sv.z, acc.z); acc.w = fmaf(di, sv.w, acc.w);
        float4 v;
        v.x = acc.x * di; v.y = acc.y * di; v.z = acc.z * di; v.w = acc.w * di;
        if (bias) {
            float4 bv = *reinterpret_cast<const float4*>(&bias[fl]);
            v.x += bv.x; v.y += bv.y; v.z += bv.z; v.w += bv.w;
        }
        if (relu) {
            v.x = fmaxf(v.x, 0.f); v.y = fmaxf(v.y, 0.f);
            v.z = fmaxf(v.z, 0.f); v.w = fmaxf(v.w, 0.f);
        }
        *reinterpret_cast<float4*>(&out[(size_t)node * 64 + fl]) = v;
    }
}

// ---------------- GEMM2: [M,64] @ [64,128] + b -> [M,128] ----------------
__global__ __launch_bounds__(256) void gemm2_kernel(const float* __restrict__ A,
                                                    const float* __restrict__ W,
                                                    const float* __restrict__ bias,
                                                    float* __restrict__ out, int M) {
    __shared__ float as[64][65];
    __shared__ float ws[64][128];
    int tid = threadIdx.x;
    int bm = blockIdx.x * 64;
    int ty = tid >> 4, tx = tid & 15;
#pragma unroll
    for (int i = 0; i < 4; ++i) {
        int lin = (tid << 2) + i;
        int r = lin >> 4;
        int c = (lin & 15) << 2;
        float4 v = make_float4(0.f, 0.f, 0.f, 0.f);
        int gr = bm + r;
        if (gr < M) v = *reinterpret_cast<const float4*>(&A[(size_t)gr * 64 + c]);
        as[r][c] = v.x; as[r][c + 1] = v.y; as[r][c + 2] = v.z; as[r][c + 3] = v.w;
    }
#pragma unroll
    for (int i = 0; i < 8; ++i) {
        int lin = tid + (i << 8);              // 0..2047 float4s
        int r = lin >> 5;
        int c = (lin & 31) << 2;
        *reinterpret_cast<float4*>(&ws[r][c]) =
            *reinterpret_cast<const float4*>(&W[(size_t)r * 128 + c]);
    }
    __syncthreads();
    float acc[4][8] = {};
#pragma unroll 8
    for (int kk = 0; kk < 64; ++kk) {
        float a[4];
#pragma unroll
        for (int i = 0; i < 4; ++i) a[i] = as[ty * 4 + i][kk];
        float b[8];
        float4 b0 = *reinterpret_cast<const float4*>(&ws[kk][tx * 8]);
        float4 b1 = *reinterpret_cast<const float4*>(&ws[kk][tx * 8 + 4]);
        b[0] = b0.x; b[1] = b0.y; b[2] = b0.z; b[3] = b0.w;
        b[4] = b1.x; b[5] = b1.y; b[6] = b1.z; b[7] = b1.w;
#pragma unroll
        for (int i = 0; i < 4; ++i)
#pragma unroll
            for (int j = 0; j < 8; ++j)
                acc[i][j] = fmaf(a[i], b[j], acc[i][j]);
    }
#pragma unroll
    for (int i = 0; i < 4; ++i) {
        int gr = bm + ty * 4 + i;
        if (gr >= M) continue;
#pragma unroll
        for (int jv = 0; jv < 2; ++jv) {
            int cbase = tx * 8 + jv * 4;
            float4 o;
            o.x = acc[i][jv * 4 + 0] + bias[cbase + 0];
            o.y = acc[i][jv * 4 + 1] + bias[cbase + 1];
            o.z = acc[i][jv * 4 + 2] + bias[cbase + 2];
            o.w = acc[i][jv * 4 + 3] + bias[cbase + 3];
            *reinterpret_cast<float4*>(&out[(size_t)gr * 128 + cbase]) = o;
        }
    }
}

extern "C" void kernel_launch(void* const* d_in, const int* in_sizes, int n_in,
                              void* d_out, int out_size, void* d_ws, size_t ws_size,
                              hipStream_t stream) {
    const float* x  = (const float*)d_in[0];
    const int*   ei = (const int*)d_in[1];
    const float* W1 = (const float*)d_in[2];
    const float* b1 = (const float*)d_in[3];
    const float* W2 = (const float*)d_in[4];
    const float* b2 = (const float*)d_in[5];
    float* out = (float*)d_out;
    const int n = NNODES;
    const int E = in_sizes[1] / 2;
    const int CE = (E + NCHUNK - 1) / NCHUNK;

    char* w = (char*)d_ws;
    auto alloc = [&](size_t bytes) {
        char* p = w;
        w += (bytes + 255) & ~(size_t)255;
        return p;
    };
    int*   flag   = (int*)  alloc(4);
    int*   indeg  = (int*)  alloc((size_t)n * 4);
    float* dinv   = (float*)alloc((size_t)n * 4);
    int*   ptr    = (int*)  alloc((size_t)(n + 1) * 4);
    int*   cursor = (int*)  alloc((size_t)n * 4);
    int*   bsum   = (int*)  alloc(128 * 4);
    int*   boff   = (int*)  alloc(128 * 4);
    int2*  cw     = (int2*) alloc((size_t)E * 8);
    float* H1     = (float*)alloc((size_t)n * 64 * 4);
    float* h1     = (float*)alloc((size_t)n * 64 * 4);
    float* A2     = H1;   // H1 dead after first aggregation

    hipMemsetAsync(indeg, 0, (size_t)n * 4, stream);

    int nb = (n + 255) / 256;
    int sb = (n + SCAN_ELEMS - 1) / SCAN_ELEMS;   // 98 scan blocks
    detect_kernel<<<1, 128, 0, stream>>>(ei, flag);
    degree8_kernel<<<NPART * NCHUNK, 256, 0, stream>>>(ei, indeg, E, CE, flag);
    dinv_kernel<<<nb, 256, 0, stream>>>(indeg, dinv, n);
    scan_partial_kernel<<<sb, 256, 0, stream>>>(indeg, bsum, n);
    scan_partials_kernel<<<1, 128, 0, stream>>>(bsum, boff, &ptr[n], sb);
    scan_write_kernel<<<sb, 256, 0, stream>>>(indeg, boff, ptr, n);
    cursor_kernel<<<nb, 256, 0, stream>>>(ptr, cursor, n);
    fill8_kernel<<<NPART * NCHUNK, 256, 0, stream>>>(ei, dinv, cursor, cw, E, CE, flag);

    gemm1_kernel<<<(n + 63) / 64, 256, 0, stream>>>(x, W1, H1, n);
    aggregate_kernel<<<(n + 3) / 4, 256, 0, stream>>>(H1, ptr, cw, dinv, b1, h1, n, 1);
    aggregate_kernel<<<(n + 3) / 4, 256, 0, stream>>>(h1, ptr, cw, dinv, nullptr, A2, n, 0);
    gemm2_kernel<<<(n + 63) / 64, 256, 0, stream>>>(A2, W2, b2, out, n);
}